// Round 2
// baseline (6582.928 us; speedup 1.0000x reference)
//
#include <hip/hip_runtime.h>
#include <hip/hip_bf16.h>
#include <math.h>

#define B_ 16
#define S_ 512
#define E_ 300
#define H_ 512
#define V_ 10000
#define BS_ (B_ * S_)  // 8192

#define GBLK 64        // blocks in the scan
#define JPB (H_ / GBLK)  // 8 output rows per block

// ---------------------------------------------------------------------------
// K0: per-call init — zero h-ring buffer 0, reset barrier state.
// ---------------------------------------------------------------------------
__global__ __launch_bounds__(256) void k0_init(float* __restrict__ hring,
                                               int* __restrict__ bar) {
  const int idx = blockIdx.x * 256 + threadIdx.x;
  if (idx < B_ * H_) hring[idx] = 0.f;
  if (idx == 0) { bar[0] = 0; bar[1] = 0; }
}

// ---------------------------------------------------------------------------
// K1: xw[bs,h] = sum_e x[bs,e] * W_ih[h,e] + b_ih[h] + b_hh[h]
// ---------------------------------------------------------------------------
__global__ __launch_bounds__(256) void k1_xw(const float* __restrict__ x,
                                             const float* __restrict__ W_ih,
                                             const float* __restrict__ b_ih,
                                             const float* __restrict__ b_hh,
                                             float* __restrict__ xw) {
  __shared__ float As[16][301];
  __shared__ float Ws[16][301];
  const int row0 = blockIdx.x * 16;  // bs
  const int col0 = blockIdx.y * 16;  // h
  const int tid = threadIdx.x;
  for (int idx = tid; idx < 16 * E_; idx += 256) {
    int r = idx / E_, c = idx - r * E_;
    As[r][c] = x[(size_t)(row0 + r) * E_ + c];
    Ws[r][c] = W_ih[(size_t)(col0 + r) * E_ + c];
  }
  __syncthreads();
  const int i = tid >> 4, j = tid & 15;
  float acc = 0.f;
#pragma unroll 4
  for (int e = 0; e < E_; ++e) acc += As[i][e] * Ws[j][e];
  const int h = col0 + j;
  xw[(size_t)(row0 + i) * H_ + h] = acc + b_ih[h] + b_hh[h];
}

// ---------------------------------------------------------------------------
// Device-scope grid barrier (sense via monotone generation counter).
// Requires all GBLK blocks co-resident (GBLK=64 << 256 CUs, 1 wg/CU).
// ---------------------------------------------------------------------------
__device__ __forceinline__ void grid_barrier(int* cnt, int* gen, int nblk) {
  __syncthreads();  // all waves' stores drained (compiler emits vmcnt(0))
  if (threadIdx.x == 0) {
    __threadfence();  // release: L2 writeback so other XCDs can see h
    const int g = __hip_atomic_load(gen, __ATOMIC_RELAXED, __HIP_MEMORY_SCOPE_AGENT);
    const int old =
        __hip_atomic_fetch_add(cnt, 1, __ATOMIC_ACQ_REL, __HIP_MEMORY_SCOPE_AGENT);
    if (old == nblk - 1) {
      __hip_atomic_store(cnt, 0, __ATOMIC_RELAXED, __HIP_MEMORY_SCOPE_AGENT);
      __hip_atomic_store(gen, g + 1, __ATOMIC_RELEASE, __HIP_MEMORY_SCOPE_AGENT);
    } else {
      while (__hip_atomic_load(gen, __ATOMIC_RELAXED, __HIP_MEMORY_SCOPE_AGENT) == g) {
        __builtin_amdgcn_s_sleep(1);
      }
    }
    __threadfence();  // acquire: invalidate L1/L2 so h reads are fresh
  }
  __syncthreads();
}

// ---------------------------------------------------------------------------
// K2: sequential scan, W_hh LDS-resident. Block g owns output rows
// [g*8, g*8+8) for ALL 16 batches. Per step: gather xw slice, stage full
// h_prev (16x512) to LDS, 256-FMA dot per thread (thread = b,j,half),
// shfl-pair reduce, tanh, write h_next slice + hs, grid barrier.
// Triple-buffered h ring => 1 barrier/step.
// ---------------------------------------------------------------------------
__global__ __launch_bounds__(256) void k2_scan(const float* __restrict__ xw,
                                               const float* __restrict__ W_hh,
                                               float* __restrict__ hs,
                                               float* __restrict__ hring,
                                               int* __restrict__ bar) {
  __shared__ float Wl[JPB][H_ + 4];   // row stride 516 -> bank stride 4
  __shared__ float hl[B_][H_ + 4];
  __shared__ float xwl[B_ * JPB];
  const int tid = threadIdx.x;
  const int j0 = blockIdx.x * JPB;

  // Load this block's W rows once (8 x 512 f32 = 16 KB).
  for (int k = tid; k < JPB * (H_ / 4); k += 256) {
    const int r = k / (H_ / 4), c4 = k - r * (H_ / 4);
    const float4 w = *(const float4*)&W_hh[(size_t)(j0 + r) * H_ + c4 * 4];
    *(float4*)&Wl[r][c4 * 4] = w;
  }

  const int b = tid >> 4;
  const int j = (tid >> 1) & 7;
  const int half = tid & 1;
  const int i0 = half * 256;
  __syncthreads();

  for (int t = 0; t < S_; ++t) {
    const float* hprev = hring + (t % 3) * (B_ * H_);
    float* hnext = hring + ((t + 1) % 3) * (B_ * H_);

    // xw slice for this step: 16 b x 8 j (issued early to hide latency)
    float xv = 0.f;
    if (tid < B_ * JPB) {
      const int bb = tid >> 3, jj = tid & 7;
      xv = xw[((size_t)bb * S_ + t) * H_ + j0 + jj];
    }
    // stage h_prev (16x512 f32 = 32 KB) into LDS, coalesced float4
#pragma unroll
    for (int k = 0; k < 8; ++k) {
      const int idx = tid + k * 256;          // float4 index in [0,2048)
      const int bb = idx >> 7, ii = (idx & 127) << 2;
      const float4 hv = *(const float4*)&hprev[(bb << 9) | ii];
      *(float4*)&hl[bb][ii] = hv;
    }
    if (tid < B_ * JPB) xwl[tid] = xv;
    __syncthreads();

    float acc = 0.f;
#pragma unroll
    for (int ii = 0; ii < 256; ii += 4) {
      const float4 w = *(const float4*)&Wl[j][i0 + ii];
      const float4 hv = *(const float4*)&hl[b][i0 + ii];
      acc += w.x * hv.x + w.y * hv.y + w.z * hv.z + w.w * hv.w;
    }
    acc += __shfl_xor(acc, 1);
    if (!half) {
      const float hn = tanhf(xwl[b * 8 + j] + acc);
      hnext[(b << 9) | (j0 + j)] = hn;
      hs[((size_t)b * S_ + t) * H_ + j0 + j] = hn;
    }
    grid_barrier(bar, bar + 1, GBLK);
  }
}

// ---------------------------------------------------------------------------
// K3: logits[bs,v] = sum_h hs[bs,h] * W_fc[v,h] + b_fc[v]   (into d_out)
// ---------------------------------------------------------------------------
__global__ __launch_bounds__(256) void k3_logits(const float* __restrict__ hs,
                                                 const float* __restrict__ W_fc,
                                                 const float* __restrict__ b_fc,
                                                 float* __restrict__ out) {
  __shared__ float As[8][128];
  __shared__ float Bs[8][128];
  const int m0 = blockIdx.x * 128;
  const int n0 = blockIdx.y * 128;
  const int tid = threadIdx.x;
  const int tx = tid & 15, ty = tid >> 4;
  float acc[8][8];
#pragma unroll
  for (int i = 0; i < 8; ++i)
#pragma unroll
    for (int jj = 0; jj < 8; ++jj) acc[i][jj] = 0.f;

  const int rr = tid >> 1;
  const int kq = (tid & 1) * 4;
  const bool bok = (n0 + rr) < V_;

  for (int k0 = 0; k0 < H_; k0 += 8) {
    const float4 av = *(const float4*)&hs[(size_t)(m0 + rr) * H_ + k0 + kq];
    float4 bv = make_float4(0.f, 0.f, 0.f, 0.f);
    if (bok) bv = *(const float4*)&W_fc[(size_t)(n0 + rr) * H_ + k0 + kq];
    __syncthreads();
    As[kq + 0][rr] = av.x; As[kq + 1][rr] = av.y;
    As[kq + 2][rr] = av.z; As[kq + 3][rr] = av.w;
    Bs[kq + 0][rr] = bv.x; Bs[kq + 1][rr] = bv.y;
    Bs[kq + 2][rr] = bv.z; Bs[kq + 3][rr] = bv.w;
    __syncthreads();
#pragma unroll
    for (int kk = 0; kk < 8; ++kk) {
      const float4 a0 = *(const float4*)&As[kk][ty * 8];
      const float4 a1 = *(const float4*)&As[kk][ty * 8 + 4];
      const float4 b0 = *(const float4*)&Bs[kk][tx * 8];
      const float4 b1 = *(const float4*)&Bs[kk][tx * 8 + 4];
      const float a[8] = {a0.x, a0.y, a0.z, a0.w, a1.x, a1.y, a1.z, a1.w};
      const float bb[8] = {b0.x, b0.y, b0.z, b0.w, b1.x, b1.y, b1.z, b1.w};
#pragma unroll
      for (int i = 0; i < 8; ++i)
#pragma unroll
        for (int jj = 0; jj < 8; ++jj) acc[i][jj] += a[i] * bb[jj];
    }
  }
#pragma unroll
  for (int jj = 0; jj < 8; ++jj) {
    const int v = n0 + tx * 8 + jj;
    if (v < V_) {
      const float bias = b_fc[v];
#pragma unroll
      for (int i = 0; i < 8; ++i)
        out[(size_t)(m0 + ty * 8 + i) * V_ + v] = acc[i][jj] + bias;
    }
  }
}

// ---------------------------------------------------------------------------
// K4a: per-(b,v) online max+sum over S; stores (m, 1/sum).
// ---------------------------------------------------------------------------
__global__ __launch_bounds__(256) void k4_stats(const float* __restrict__ logits,
                                                float* __restrict__ stats) {
  const int g = blockIdx.x * 256 + threadIdx.x;
  const int b = g / V_;
  const int v = g - b * V_;
  const float* p = logits + (size_t)b * S_ * V_ + v;
  float m = -3.4e38f, sum = 0.f;
  for (int s = 0; s < S_; ++s) {
    const float xv = p[(size_t)s * V_];
    if (xv > m) {
      sum = sum * __expf(m - xv) + 1.f;
      m = xv;
    } else {
      sum += __expf(xv - m);
    }
  }
  stats[2 * g] = m;
  stats[2 * g + 1] = 1.f / sum;
}

// ---------------------------------------------------------------------------
// K4b: in-place normalize: out = exp(l - m) * inv_sum
// ---------------------------------------------------------------------------
__global__ __launch_bounds__(256) void k4_norm(float* __restrict__ logits,
                                               const float* __restrict__ stats) {
  const size_t idx = (size_t)blockIdx.x * 256 + threadIdx.x;
  const int v = (int)(idx % V_);
  const int b = (int)(idx / ((size_t)S_ * V_));
  const int g = b * V_ + v;
  const float m = stats[2 * g];
  const float inv = stats[2 * g + 1];
  logits[idx] = __expf(logits[idx] - m) * inv;
}

extern "C" void kernel_launch(void* const* d_in, const int* in_sizes, int n_in,
                              void* d_out, int out_size, void* d_ws,
                              size_t ws_size, hipStream_t stream) {
  const float* x    = (const float*)d_in[0];
  const float* W_ih = (const float*)d_in[1];
  const float* W_hh = (const float*)d_in[2];
  const float* b_ih = (const float*)d_in[3];
  const float* b_hh = (const float*)d_in[4];
  const float* W_fc = (const float*)d_in[5];
  const float* b_fc = (const float*)d_in[6];
  float* out = (float*)d_out;

  // ws layout (floats): xw | hs | stats | hring | bar
  float* ws = (float*)d_ws;
  float* xw    = ws;                              // 8192*512
  float* hs    = xw + (size_t)BS_ * H_;           // 8192*512
  float* stats = hs + (size_t)BS_ * H_;           // 2*16*10000
  float* hring = stats + (size_t)2 * B_ * V_;     // 3*16*512
  int*   bar   = (int*)(hring + (size_t)3 * B_ * H_);  // 2 ints

  k0_init<<<32, 256, 0, stream>>>(hring, bar);
  k1_xw<<<dim3(BS_ / 16, H_ / 16), 256, 0, stream>>>(x, W_ih, b_ih, b_hh, xw);
  k2_scan<<<GBLK, 256, 0, stream>>>(xw, W_hh, hs, hring, bar);
  k3_logits<<<dim3(BS_ / 128, (V_ + 127) / 128), 256, 0, stream>>>(hs, W_fc,
                                                                   b_fc, out);
  k4_stats<<<(B_ * V_) / 256, 256, 0, stream>>>(out, stats);
  k4_norm<<<(int)((size_t)BS_ * V_ / 256), 256, 0, stream>>>(out, stats);
}

// Round 3
// 3316.375 us; speedup vs baseline: 1.9850x; 1.9850x over previous
//
#include <hip/hip_runtime.h>
#include <hip/hip_bf16.h>
#include <math.h>

#define B_ 16
#define S_ 512
#define E_ 300
#define H_ 512
#define V_ 10000
#define BS_ (B_ * S_)  // 8192

#define GPB 8            // blocks per batch (sync group size)
#define JPB (H_ / GPB)   // 64 output rows per block
#define NBLK (B_ * GPB)  // 128 blocks in the scan

// ---------------------------------------------------------------------------
// K0: per-call init — zero h buffer 0 and the per-batch arrival counters.
// (graph replay safe: re-initialized every call)
// ---------------------------------------------------------------------------
__global__ __launch_bounds__(256) void k0_init(float* __restrict__ hbuf,
                                               int* __restrict__ cnt) {
  const int idx = blockIdx.x * 256 + threadIdx.x;
  if (idx < B_ * H_) hbuf[idx] = 0.f;
  if (idx < B_ * 64) cnt[idx] = 0;
}

// ---------------------------------------------------------------------------
// K1: xw[bs,h] = sum_e x[bs,e] * W_ih[h,e] + b_ih[h] + b_hh[h]
// ---------------------------------------------------------------------------
__global__ __launch_bounds__(256) void k1_xw(const float* __restrict__ x,
                                             const float* __restrict__ W_ih,
                                             const float* __restrict__ b_ih,
                                             const float* __restrict__ b_hh,
                                             float* __restrict__ xw) {
  __shared__ float As[16][301];
  __shared__ float Ws[16][301];
  const int row0 = blockIdx.x * 16;  // bs
  const int col0 = blockIdx.y * 16;  // h
  const int tid = threadIdx.x;
  for (int idx = tid; idx < 16 * E_; idx += 256) {
    int r = idx / E_, c = idx - r * E_;
    As[r][c] = x[(size_t)(row0 + r) * E_ + c];
    Ws[r][c] = W_ih[(size_t)(col0 + r) * E_ + c];
  }
  __syncthreads();
  const int i = tid >> 4, j = tid & 15;
  float acc = 0.f;
#pragma unroll 4
  for (int e = 0; e < E_; ++e) acc += As[i][e] * Ws[j][e];
  const int h = col0 + j;
  xw[(size_t)(row0 + i) * H_ + h] = acc + b_ih[h] + b_hh[h];
}

// ---------------------------------------------------------------------------
// K2: sequential scan. Block (b,g) owns output rows [g*64, g*64+64) of batch
// b, with its W_hh slice in VGPRs (32 float4 per thread, loaded once).
// Per step: stage h_prev (512 f32) from MALL via relaxed agent (sc1,
// cache-bypassing) atomic loads into LDS; broadcast-dot from LDS into the
// VGPR-resident W; shfl-pair reduce over the 4-way k-split; tanh; sc1 store
// of the 64 new h values; one RELEASE fetch_add on the per-batch counter
// (cumulative, 8 arrivals/step); spin until 8*(t+1). Double-buffered h is
// race-free: every read of buf_t precedes arrival(t), every write of buf_t
// (again) happens after barrier(t) passed.
// ---------------------------------------------------------------------------
__global__ __launch_bounds__(256, 2) void k2_scan(const float* __restrict__ xw,
                                                  const float* __restrict__ W_hh,
                                                  float* __restrict__ hs,
                                                  float* __restrict__ hbuf,
                                                  int* __restrict__ cnt) {
  const int b = blockIdx.x >> 3;
  const int g = blockIdx.x & 7;
  const int j0 = g * JPB;
  const int tid = threadIdx.x;
  const int j = tid >> 2;  // 0..63 output row within slice
  const int q = tid & 3;   // 0..3  k-quarter

  // W slice into registers: W_hh[j0+j][q*128 .. q*128+127]  (128 f32)
  float4 w[32];
  const float* wrow = &W_hh[(size_t)(j0 + j) * H_ + q * 128];
#pragma unroll
  for (int k = 0; k < 32; ++k) w[k] = *(const float4*)&wrow[k * 4];

  __shared__ float hl[4 * 132];  // 4 k-quarters, stride 132 (bank-spread)
  __shared__ float xwl[JPB];
  int* mycnt = cnt + b * 64;  // per-batch counter, 256 B apart

  const int wq0 = tid >> 7, wk0 = tid & 127;  // LDS slot for h[tid]

  for (int t = 0; t < S_; ++t) {
    const int* src = (const int*)(hbuf + (t & 1) * (B_ * H_) + (size_t)b * H_);
    int* dst = (int*)(hbuf + ((t + 1) & 1) * (B_ * H_) + (size_t)b * H_);

    // stage h_prev: 512 dwords, 2 per thread, MALL-direct (sc1)
    const int h0 =
        __hip_atomic_load(&src[tid], __ATOMIC_RELAXED, __HIP_MEMORY_SCOPE_AGENT);
    const int h1 = __hip_atomic_load(&src[tid + 256], __ATOMIC_RELAXED,
                                     __HIP_MEMORY_SCOPE_AGENT);
    if (tid < JPB) xwl[tid] = xw[((size_t)b * S_ + t) * H_ + j0 + tid];
    hl[wq0 * 132 + wk0] = __int_as_float(h0);
    hl[(wq0 + 2) * 132 + wk0] = __int_as_float(h1);
    __syncthreads();

    // dot: thread (j,q) does h[q*128..+128) . W[j][q*128..+128)
    float acc = 0.f;
    const float* hq = &hl[q * 132];
#pragma unroll
    for (int k = 0; k < 32; ++k) {
      const float4 hv = *(const float4*)&hq[k * 4];
      acc += w[k].x * hv.x + w[k].y * hv.y + w[k].z * hv.z + w[k].w * hv.w;
    }
    acc += __shfl_xor(acc, 1);
    acc += __shfl_xor(acc, 2);
    if (q == 0) {
      const float hn = tanhf(xwl[j] + acc);
      __hip_atomic_store(&dst[j0 + j], __float_as_int(hn), __ATOMIC_RELAXED,
                         __HIP_MEMORY_SCOPE_AGENT);
      hs[((size_t)b * S_ + t) * H_ + j0 + j] = hn;
    }
    __syncthreads();  // all waves' stores vmcnt-drained at barrier entry
    if (tid == 0) {
      __hip_atomic_fetch_add(mycnt, 1, __ATOMIC_RELEASE,
                             __HIP_MEMORY_SCOPE_AGENT);
      const int target = GPB * (t + 1);
      while (__hip_atomic_load(mycnt, __ATOMIC_RELAXED,
                               __HIP_MEMORY_SCOPE_AGENT) < target) {
        __builtin_amdgcn_s_sleep(1);
      }
    }
    __syncthreads();
  }
}

// ---------------------------------------------------------------------------
// K3: logits[bs,v] = sum_h hs[bs,h] * W_fc[v,h] + b_fc[v]   (into d_out)
// ---------------------------------------------------------------------------
__global__ __launch_bounds__(256) void k3_logits(const float* __restrict__ hs,
                                                 const float* __restrict__ W_fc,
                                                 const float* __restrict__ b_fc,
                                                 float* __restrict__ out) {
  __shared__ float As[8][128];
  __shared__ float Bs[8][128];
  const int m0 = blockIdx.x * 128;
  const int n0 = blockIdx.y * 128;
  const int tid = threadIdx.x;
  const int tx = tid & 15, ty = tid >> 4;
  float acc[8][8];
#pragma unroll
  for (int i = 0; i < 8; ++i)
#pragma unroll
    for (int jj = 0; jj < 8; ++jj) acc[i][jj] = 0.f;

  const int rr = tid >> 1;
  const int kq = (tid & 1) * 4;
  const bool bok = (n0 + rr) < V_;

  for (int k0 = 0; k0 < H_; k0 += 8) {
    const float4 av = *(const float4*)&hs[(size_t)(m0 + rr) * H_ + k0 + kq];
    float4 bv = make_float4(0.f, 0.f, 0.f, 0.f);
    if (bok) bv = *(const float4*)&W_fc[(size_t)(n0 + rr) * H_ + k0 + kq];
    __syncthreads();
    As[kq + 0][rr] = av.x; As[kq + 1][rr] = av.y;
    As[kq + 2][rr] = av.z; As[kq + 3][rr] = av.w;
    Bs[kq + 0][rr] = bv.x; Bs[kq + 1][rr] = bv.y;
    Bs[kq + 2][rr] = bv.z; Bs[kq + 3][rr] = bv.w;
    __syncthreads();
#pragma unroll
    for (int kk = 0; kk < 8; ++kk) {
      const float4 a0 = *(const float4*)&As[kk][ty * 8];
      const float4 a1 = *(const float4*)&As[kk][ty * 8 + 4];
      const float4 b0 = *(const float4*)&Bs[kk][tx * 8];
      const float4 b1 = *(const float4*)&Bs[kk][tx * 8 + 4];
      const float a[8] = {a0.x, a0.y, a0.z, a0.w, a1.x, a1.y, a1.z, a1.w};
      const float bb[8] = {b0.x, b0.y, b0.z, b0.w, b1.x, b1.y, b1.z, b1.w};
#pragma unroll
      for (int i = 0; i < 8; ++i)
#pragma unroll
        for (int jj = 0; jj < 8; ++jj) acc[i][jj] += a[i] * bb[jj];
    }
  }
#pragma unroll
  for (int jj = 0; jj < 8; ++jj) {
    const int v = n0 + tx * 8 + jj;
    if (v < V_) {
      const float bias = b_fc[v];
#pragma unroll
      for (int i = 0; i < 8; ++i)
        out[(size_t)(m0 + ty * 8 + i) * V_ + v] = acc[i][jj] + bias;
    }
  }
}

// ---------------------------------------------------------------------------
// K4a: per-(b,v) online max+sum over S; stores (m, 1/sum).
// ---------------------------------------------------------------------------
__global__ __launch_bounds__(256) void k4_stats(const float* __restrict__ logits,
                                                float* __restrict__ stats) {
  const int g = blockIdx.x * 256 + threadIdx.x;
  const int b = g / V_;
  const int v = g - b * V_;
  const float* p = logits + (size_t)b * S_ * V_ + v;
  float m = -3.4e38f, sum = 0.f;
  for (int s = 0; s < S_; ++s) {
    const float xv = p[(size_t)s * V_];
    if (xv > m) {
      sum = sum * __expf(m - xv) + 1.f;
      m = xv;
    } else {
      sum += __expf(xv - m);
    }
  }
  stats[2 * g] = m;
  stats[2 * g + 1] = 1.f / sum;
}

// ---------------------------------------------------------------------------
// K4b: in-place normalize: out = exp(l - m) * inv_sum
// ---------------------------------------------------------------------------
__global__ __launch_bounds__(256) void k4_norm(float* __restrict__ logits,
                                               const float* __restrict__ stats) {
  const size_t idx = (size_t)blockIdx.x * 256 + threadIdx.x;
  const int v = (int)(idx % V_);
  const int b = (int)(idx / ((size_t)S_ * V_));
  const int g = b * V_ + v;
  const float m = stats[2 * g];
  const float inv = stats[2 * g + 1];
  logits[idx] = __expf(logits[idx] - m) * inv;
}

extern "C" void kernel_launch(void* const* d_in, const int* in_sizes, int n_in,
                              void* d_out, int out_size, void* d_ws,
                              size_t ws_size, hipStream_t stream) {
  const float* x    = (const float*)d_in[0];
  const float* W_ih = (const float*)d_in[1];
  const float* W_hh = (const float*)d_in[2];
  const float* b_ih = (const float*)d_in[3];
  const float* b_hh = (const float*)d_in[4];
  const float* W_fc = (const float*)d_in[5];
  const float* b_fc = (const float*)d_in[6];
  float* out = (float*)d_out;

  // ws layout (floats): xw | hs | stats | hbuf(2*B*H) | cnt(16*64 ints)
  float* ws = (float*)d_ws;
  float* xw    = ws;                              // 8192*512
  float* hs    = xw + (size_t)BS_ * H_;           // 8192*512
  float* stats = hs + (size_t)BS_ * H_;           // 2*16*10000
  float* hbuf  = stats + (size_t)2 * B_ * V_;     // 2*16*512
  int*   cnt   = (int*)(hbuf + (size_t)2 * B_ * H_);  // 16*64 ints

  k0_init<<<64, 256, 0, stream>>>(hbuf, cnt);
  k1_xw<<<dim3(BS_ / 16, H_ / 16), 256, 0, stream>>>(x, W_ih, b_ih, b_hh, xw);
  k2_scan<<<NBLK, 256, 0, stream>>>(xw, W_hh, hs, hbuf, cnt);
  k3_logits<<<dim3(BS_ / 128, (V_ + 127) / 128), 256, 0, stream>>>(hs, W_fc,
                                                                   b_fc, out);
  k4_stats<<<(B_ * V_) / 256, 256, 0, stream>>>(out, stats);
  k4_norm<<<(int)((size_t)BS_ * V_ / 256), 256, 0, stream>>>(out, stats);
}

// Round 4
// 2827.103 us; speedup vs baseline: 2.3285x; 1.1731x over previous
//
#include <hip/hip_runtime.h>
#include <hip/hip_bf16.h>
#include <math.h>

#define B_ 16
#define S_ 512
#define E_ 300
#define H_ 512
#define V_ 10000
#define BS_ (B_ * S_)  // 8192

#define GPB 4            // blocks per batch (k-split)
#define KPB (H_ / GPB)   // 128 k per block
#define NBLK (B_ * GPB)  // 64 blocks in the scan

// ---------------------------------------------------------------------------
// K0: invalidate all partial-exchange tags (64-bit words, hi32 = 0xFFFFFFFF).
// Required every call: previous call leaves tags 0..511 behind which would
// falsely match. In-stream, ~512 KB write.
// ---------------------------------------------------------------------------
__global__ __launch_bounds__(256) void k0_init(unsigned long long* __restrict__ part) {
  const int idx = blockIdx.x * 256 + threadIdx.x;
  part[idx] = 0xFFFFFFFF00000000ull;
}

// ---------------------------------------------------------------------------
// K1: xw[bs,h] = sum_e x[bs,e] * W_ih[h,e] + b_ih[h] + b_hh[h]
// ---------------------------------------------------------------------------
__global__ __launch_bounds__(256) void k1_xw(const float* __restrict__ x,
                                             const float* __restrict__ W_ih,
                                             const float* __restrict__ b_ih,
                                             const float* __restrict__ b_hh,
                                             float* __restrict__ xw) {
  __shared__ float As[16][301];
  __shared__ float Ws[16][301];
  const int row0 = blockIdx.x * 16;  // bs
  const int col0 = blockIdx.y * 16;  // h
  const int tid = threadIdx.x;
  for (int idx = tid; idx < 16 * E_; idx += 256) {
    int r = idx / E_, c = idx - r * E_;
    As[r][c] = x[(size_t)(row0 + r) * E_ + c];
    Ws[r][c] = W_ih[(size_t)(col0 + r) * E_ + c];
  }
  __syncthreads();
  const int i = tid >> 4, j = tid & 15;
  float acc = 0.f;
#pragma unroll 4
  for (int e = 0; e < E_; ++e) acc += As[i][e] * Ws[j][e];
  const int h = col0 + j;
  xw[(size_t)(row0 + i) * H_ + h] = acc + b_ih[h] + b_hh[h];
}

// ---------------------------------------------------------------------------
// K2: sequential scan, k-split + tagged-push exchange.
// Block (b,g), 512 threads, thread = output row j. Holds W_hh[j][g*128 ..
// g*128+127] in 32 float4 VGPRs. Per step:
//   dot (LDS-broadcast h, VGPR W) -> publish (t<<32|f32) u64 sc1 store
//   -> __syncthreads -> poll 3 partners' words until tag==t -> combine
//   -> h_j = tanh(xw_j + total) -> LDS h[j] -> __syncthreads.
// All 4 blocks redundantly hold full h in LDS => only partials ever cross
// the fabric (1 MALL RT/step). Slot reuse at distance 2 is race-free:
// block g writes slot(t) again at t+2 only after reading every partner's
// t+1 partial, which that partner published only after consuming g's t.
// ---------------------------------------------------------------------------
__global__ __launch_bounds__(512) void k2_scan(const float* __restrict__ xw,
                                               const float* __restrict__ W_hh,
                                               float* __restrict__ hs,
                                               unsigned long long* __restrict__ part) {
  const int b = blockIdx.x >> 2;
  const int g = blockIdx.x & 3;
  const int j = threadIdx.x;  // 0..511

  // W slice into registers: W_hh[j][g*128 .. +128)  (128 f32 = 32 float4)
  float4 w[32];
  const float* wrow = &W_hh[(size_t)j * H_ + g * KPB];
#pragma unroll
  for (int k = 0; k < 32; ++k) w[k] = *(const float4*)&wrow[k * 4];

  __shared__ float hl[H_];
  hl[j] = 0.f;

  const int pg0 = (g + 1) & 3, pg1 = (g + 2) & 3, pg2 = (g + 3) & 3;
  unsigned long long* const pbase = part + (size_t)b * 2 * GPB * H_;

  float xwv = xw[(size_t)b * S_ * H_ + j];  // t = 0 slice
  __syncthreads();

  for (int t = 0; t < S_; ++t) {
    const int slot = t & 1;
    // dot over this block's k-quarter; h broadcast from LDS
    const float* hq = &hl[g * KPB];
    float p = 0.f;
#pragma unroll
    for (int k = 0; k < 32; ++k) {
      const float4 hv = *(const float4*)&hq[k * 4];
      p += w[k].x * hv.x + w[k].y * hv.y + w[k].z * hv.z + w[k].w * hv.w;
    }
    // publish tagged partial (single 8B atomic store, MALL-visible)
    const unsigned long long pk =
        ((unsigned long long)(unsigned)t << 32) | (unsigned)__float_as_uint(p);
    __hip_atomic_store(&pbase[(slot * GPB + g) * H_ + j], pk, __ATOMIC_RELAXED,
                       __HIP_MEMORY_SCOPE_AGENT);
    // prefetch next step's xw while partners compute
    const int tn = (t + 1 < S_) ? t + 1 : t;
    const float xw_next = xw[((size_t)b * S_ + tn) * H_ + j];
    __syncthreads();  // all dots done (no thread still reads old hl)

    // poll partners' partials for row j
    float tot = p;
    {
      unsigned long long v;
      const unsigned long long* a0 = &pbase[(slot * GPB + pg0) * H_ + j];
      const unsigned long long* a1 = &pbase[(slot * GPB + pg1) * H_ + j];
      const unsigned long long* a2 = &pbase[(slot * GPB + pg2) * H_ + j];
      do { v = __hip_atomic_load(a0, __ATOMIC_RELAXED, __HIP_MEMORY_SCOPE_AGENT);
      } while ((unsigned)(v >> 32) != (unsigned)t);
      tot += __uint_as_float((unsigned)v);
      do { v = __hip_atomic_load(a1, __ATOMIC_RELAXED, __HIP_MEMORY_SCOPE_AGENT);
      } while ((unsigned)(v >> 32) != (unsigned)t);
      tot += __uint_as_float((unsigned)v);
      do { v = __hip_atomic_load(a2, __ATOMIC_RELAXED, __HIP_MEMORY_SCOPE_AGENT);
      } while ((unsigned)(v >> 32) != (unsigned)t);
      tot += __uint_as_float((unsigned)v);
    }
    const float hn = tanhf(xwv + tot);
    hl[j] = hn;
    if (g == 0) hs[((size_t)b * S_ + t) * H_ + j] = hn;
    xwv = xw_next;
    __syncthreads();  // h fully updated before next dot
  }
}

// ---------------------------------------------------------------------------
// K3: logits[bs,v] = sum_h hs[bs,h] * W_fc[v,h] + b_fc[v]   (into d_out)
// ---------------------------------------------------------------------------
__global__ __launch_bounds__(256) void k3_logits(const float* __restrict__ hs,
                                                 const float* __restrict__ W_fc,
                                                 const float* __restrict__ b_fc,
                                                 float* __restrict__ out) {
  __shared__ float As[8][128];
  __shared__ float Bs[8][128];
  const int m0 = blockIdx.x * 128;
  const int n0 = blockIdx.y * 128;
  const int tid = threadIdx.x;
  const int tx = tid & 15, ty = tid >> 4;
  float acc[8][8];
#pragma unroll
  for (int i = 0; i < 8; ++i)
#pragma unroll
    for (int jj = 0; jj < 8; ++jj) acc[i][jj] = 0.f;

  const int rr = tid >> 1;
  const int kq = (tid & 1) * 4;
  const bool bok = (n0 + rr) < V_;

  for (int k0 = 0; k0 < H_; k0 += 8) {
    const float4 av = *(const float4*)&hs[(size_t)(m0 + rr) * H_ + k0 + kq];
    float4 bv = make_float4(0.f, 0.f, 0.f, 0.f);
    if (bok) bv = *(const float4*)&W_fc[(size_t)(n0 + rr) * H_ + k0 + kq];
    __syncthreads();
    As[kq + 0][rr] = av.x; As[kq + 1][rr] = av.y;
    As[kq + 2][rr] = av.z; As[kq + 3][rr] = av.w;
    Bs[kq + 0][rr] = bv.x; Bs[kq + 1][rr] = bv.y;
    Bs[kq + 2][rr] = bv.z; Bs[kq + 3][rr] = bv.w;
    __syncthreads();
#pragma unroll
    for (int kk = 0; kk < 8; ++kk) {
      const float4 a0 = *(const float4*)&As[kk][ty * 8];
      const float4 a1 = *(const float4*)&As[kk][ty * 8 + 4];
      const float4 b0 = *(const float4*)&Bs[kk][tx * 8];
      const float4 b1 = *(const float4*)&Bs[kk][tx * 8 + 4];
      const float a[8] = {a0.x, a0.y, a0.z, a0.w, a1.x, a1.y, a1.z, a1.w};
      const float bb[8] = {b0.x, b0.y, b0.z, b0.w, b1.x, b1.y, b1.z, b1.w};
#pragma unroll
      for (int i = 0; i < 8; ++i)
#pragma unroll
        for (int jj = 0; jj < 8; ++jj) acc[i][jj] += a[i] * bb[jj];
    }
  }
#pragma unroll
  for (int jj = 0; jj < 8; ++jj) {
    const int v = n0 + tx * 8 + jj;
    if (v < V_) {
      const float bias = b_fc[v];
#pragma unroll
      for (int i = 0; i < 8; ++i)
        out[(size_t)(m0 + ty * 8 + i) * V_ + v] = acc[i][jj] + bias;
    }
  }
}

// ---------------------------------------------------------------------------
// K4a: per-(b,v) online max+sum over S; stores (m, 1/sum).
// ---------------------------------------------------------------------------
__global__ __launch_bounds__(256) void k4_stats(const float* __restrict__ logits,
                                                float* __restrict__ stats) {
  const int g = blockIdx.x * 256 + threadIdx.x;
  const int b = g / V_;
  const int v = g - b * V_;
  const float* p = logits + (size_t)b * S_ * V_ + v;
  float m = -3.4e38f, sum = 0.f;
  for (int s = 0; s < S_; ++s) {
    const float xv = p[(size_t)s * V_];
    if (xv > m) {
      sum = sum * __expf(m - xv) + 1.f;
      m = xv;
    } else {
      sum += __expf(xv - m);
    }
  }
  stats[2 * g] = m;
  stats[2 * g + 1] = 1.f / sum;
}

// ---------------------------------------------------------------------------
// K4b: in-place normalize: out = exp(l - m) * inv_sum
// ---------------------------------------------------------------------------
__global__ __launch_bounds__(256) void k4_norm(float* __restrict__ logits,
                                               const float* __restrict__ stats) {
  const size_t idx = (size_t)blockIdx.x * 256 + threadIdx.x;
  const int v = (int)(idx % V_);
  const int b = (int)(idx / ((size_t)S_ * V_));
  const int g = b * V_ + v;
  const float m = stats[2 * g];
  const float inv = stats[2 * g + 1];
  logits[idx] = __expf(logits[idx] - m) * inv;
}

extern "C" void kernel_launch(void* const* d_in, const int* in_sizes, int n_in,
                              void* d_out, int out_size, void* d_ws,
                              size_t ws_size, hipStream_t stream) {
  const float* x    = (const float*)d_in[0];
  const float* W_ih = (const float*)d_in[1];
  const float* W_hh = (const float*)d_in[2];
  const float* b_ih = (const float*)d_in[3];
  const float* b_hh = (const float*)d_in[4];
  const float* W_fc = (const float*)d_in[5];
  const float* b_fc = (const float*)d_in[6];
  float* out = (float*)d_out;

  // ws layout (floats): xw | hs | stats | part (u64[16*2*4*512] = 512 KB)
  float* ws = (float*)d_ws;
  float* xw    = ws;                              // 8192*512
  float* hs    = xw + (size_t)BS_ * H_;           // 8192*512
  float* stats = hs + (size_t)BS_ * H_;           // 2*16*10000
  unsigned long long* part =
      (unsigned long long*)(stats + (size_t)2 * B_ * V_);  // 65536 u64

  k0_init<<<(B_ * 2 * GPB * H_) / 256, 256, 0, stream>>>(part);
  k1_xw<<<dim3(BS_ / 16, H_ / 16), 256, 0, stream>>>(x, W_ih, b_ih, b_hh, xw);
  k2_scan<<<NBLK, 512, 0, stream>>>(xw, W_hh, hs, part);
  k3_logits<<<dim3(BS_ / 128, (V_ + 127) / 128), 256, 0, stream>>>(hs, W_fc,
                                                                   b_fc, out);
  k4_stats<<<(B_ * V_) / 256, 256, 0, stream>>>(out, stats);
  k4_norm<<<(int)((size_t)BS_ * V_ / 256), 256, 0, stream>>>(out, stats);
}

// Round 5
// 2209.079 us; speedup vs baseline: 2.9799x; 1.2798x over previous
//
#include <hip/hip_runtime.h>
#include <hip/hip_bf16.h>
#include <math.h>

#define B_ 16
#define S_ 512
#define E_ 300
#define H_ 512
#define V_ 10000
#define BS_ (B_ * S_)  // 8192

#define GPB 4            // blocks per batch (k-split)
#define NBLK (B_ * GPB)  // 64 blocks in the scan

typedef __attribute__((ext_vector_type(4))) float f32x4;
typedef __attribute__((ext_vector_type(8))) short bf16x8;

// ---------------------------------------------------------------------------
// K0: invalidate exchange tags (prev call leaves tags 0..511 that would match)
// ---------------------------------------------------------------------------
__global__ __launch_bounds__(256) void k0_init(unsigned long long* __restrict__ part) {
  const int idx = blockIdx.x * 256 + threadIdx.x;
  part[idx] = 0xFFFFFFFF00000000ull;
}

// ---------------------------------------------------------------------------
// K1: xw[bs,h] = sum_e x[bs,e] * W_ih[h,e] + b_ih[h] + b_hh[h]
// ---------------------------------------------------------------------------
__global__ __launch_bounds__(256) void k1_xw(const float* __restrict__ x,
                                             const float* __restrict__ W_ih,
                                             const float* __restrict__ b_ih,
                                             const float* __restrict__ b_hh,
                                             float* __restrict__ xw) {
  __shared__ float As[16][301];
  __shared__ float Ws[16][301];
  const int row0 = blockIdx.x * 16;
  const int col0 = blockIdx.y * 16;
  const int tid = threadIdx.x;
  for (int idx = tid; idx < 16 * E_; idx += 256) {
    int r = idx / E_, c = idx - r * E_;
    As[r][c] = x[(size_t)(row0 + r) * E_ + c];
    Ws[r][c] = W_ih[(size_t)(col0 + r) * E_ + c];
  }
  __syncthreads();
  const int i = tid >> 4, j = tid & 15;
  float acc = 0.f;
#pragma unroll 4
  for (int e = 0; e < E_; ++e) acc += As[i][e] * Ws[j][e];
  const int h = col0 + j;
  xw[(size_t)(row0 + i) * H_ + h] = acc + b_ih[h] + b_hh[h];
}

// ---------------------------------------------------------------------------
// Relaxed agent-scope 8B atomic load (MALL-coherent)
// ---------------------------------------------------------------------------
__device__ __forceinline__ unsigned long long pload(
    const unsigned long long* p) {
  return __hip_atomic_load(p, __ATOMIC_RELAXED, __HIP_MEMORY_SCOPE_AGENT);
}

// ---------------------------------------------------------------------------
// K2: scan. Block (b,g): k-quarter g. 1024 threads, thread=(j=tid>>1,
// half=tid&1) holds W_hh[j][g*128+half*64 .. +64) in 16 float4 VGPRs
// (launch_bounds(1024,4) -> 128-VGPR cap -> residency fits).
// Per step: LDS-broadcast dot (64 f32) -> shfl_xor(1) combine -> even lanes
// publish tagged u64 partial -> poll 3 partners (loads issued concurrently)
// -> tanh -> write h to double-buffered LDS -> ONE barrier.
// Slot reuse at distance 2 race-free (partner consumed t before publishing
// t+1, which we consume before writing t+2).
// ---------------------------------------------------------------------------
__global__ __launch_bounds__(1024, 4) void k2_scan(
    const float* __restrict__ xw, const float* __restrict__ W_hh,
    float* __restrict__ hs, unsigned long long* __restrict__ part) {
  const int b = blockIdx.x >> 2;
  const int g = blockIdx.x & 3;
  const int tid = threadIdx.x;
  const int j = tid >> 1;
  const int half = tid & 1;
  const int kbase = g * 128 + half * 64;

  float4 w[16];
  const float* wrow = &W_hh[(size_t)j * H_ + kbase];
#pragma unroll
  for (int k = 0; k < 16; ++k) w[k] = *(const float4*)&wrow[k * 4];

  __shared__ float hl[2][H_];
  if (tid < H_) hl[0][tid] = 0.f;

  unsigned long long* const pbase = part + (size_t)b * (2 * GPB * H_);
  const int pg0 = (g + 1) & 3, pg1 = (g + 2) & 3, pg2 = (g + 3) & 3;

  float xwv = xw[(size_t)b * S_ * H_ + j];
  __syncthreads();

  for (int t = 0; t < S_; ++t) {
    const int cur = t & 1;
    const int slot = t & 1;
    const float* hq = &hl[cur][kbase];
    float p = 0.f;
#pragma unroll
    for (int k = 0; k < 16; ++k) {
      const float4 hv = *(const float4*)&hq[k * 4];
      p += w[k].x * hv.x + w[k].y * hv.y + w[k].z * hv.z + w[k].w * hv.w;
    }
    p += __shfl_xor(p, 1);  // combine half 0 + half 1

    const int tn = (t + 1 < S_) ? t + 1 : t;
    const float xw_next = xw[((size_t)b * S_ + tn) * H_ + j];

    if (half == 0) {
      const unsigned long long pk =
          ((unsigned long long)(unsigned)t << 32) |
          (unsigned long long)(unsigned)__float_as_uint(p);
      __hip_atomic_store(&pbase[(slot * GPB + g) * H_ + j], pk,
                         __ATOMIC_RELAXED, __HIP_MEMORY_SCOPE_AGENT);
      const unsigned long long* a0 = &pbase[(slot * GPB + pg0) * H_ + j];
      const unsigned long long* a1 = &pbase[(slot * GPB + pg1) * H_ + j];
      const unsigned long long* a2 = &pbase[(slot * GPB + pg2) * H_ + j];
      const unsigned ut = (unsigned)t;
      // issue all three concurrently, then retry individually
      unsigned long long v0 = pload(a0);
      unsigned long long v1 = pload(a1);
      unsigned long long v2 = pload(a2);
      while ((unsigned)(v0 >> 32) != ut) v0 = pload(a0);
      while ((unsigned)(v1 >> 32) != ut) v1 = pload(a1);
      while ((unsigned)(v2 >> 32) != ut) v2 = pload(a2);
      const float tot = p + __uint_as_float((unsigned)v0) +
                        __uint_as_float((unsigned)v1) +
                        __uint_as_float((unsigned)v2);
      const float hn = tanhf(xwv + tot);
      hl[cur ^ 1][j] = hn;
      if (g == 0) hs[((size_t)b * S_ + t) * H_ + j] = hn;
    }
    xwv = xw_next;
    __syncthreads();
  }
}

// ---------------------------------------------------------------------------
// K5: split f32 -> bf16 hi + bf16 lo (RTN both; lo = f - hi).
// 4 elems/thread via float4.
// ---------------------------------------------------------------------------
__device__ __forceinline__ unsigned short bf16_rtn(float f) {
  unsigned u = __float_as_uint(f);
  return (unsigned short)((u + 0x7FFFu + ((u >> 16) & 1u)) >> 16);
}
__global__ __launch_bounds__(256) void k5_split(const float* __restrict__ src,
                                                unsigned short* __restrict__ hi,
                                                unsigned short* __restrict__ lo,
                                                int n4) {
  const int i = blockIdx.x * 256 + threadIdx.x;
  if (i >= n4) return;
  const float4 f = *(const float4*)&src[i * 4];
  unsigned short h[4], l[4];
  const float ff[4] = {f.x, f.y, f.z, f.w};
#pragma unroll
  for (int k = 0; k < 4; ++k) {
    h[k] = bf16_rtn(ff[k]);
    const float fh = __uint_as_float((unsigned)h[k] << 16);
    l[k] = bf16_rtn(ff[k] - fh);
  }
  *(ushort4*)&hi[i * 4] = make_ushort4(h[0], h[1], h[2], h[3]);
  *(ushort4*)&lo[i * 4] = make_ushort4(l[0], l[1], l[2], l[3]);
}

// ---------------------------------------------------------------------------
// K3: logits = hs @ W_fc^T + b_fc via bf16 hi/lo split MFMA (3 products:
// hh + hl + lh; lo*lo dropped, rel err ~2^-17).
// 128x128 tile, 4 waves (2x2), 64x64/wave, BK=32, LDS row stride 40 shorts
// (80 B -> 20-bank rotation, 2-way conflict = free).
// A-frag (16x16x32): lane l -> row (l&15), k = (l>>4)*8 + 0..7.
// C/D: col = l&15, row = (l>>4)*4 + reg  [verified m89].
// ---------------------------------------------------------------------------
__global__ __launch_bounds__(256) void k3_logits(
    const unsigned short* __restrict__ Ahi, const unsigned short* __restrict__ Alo,
    const unsigned short* __restrict__ Bhi, const unsigned short* __restrict__ Blo,
    const float* __restrict__ b_fc, float* __restrict__ out) {
  __shared__ unsigned short Ah[128 * 40], Al[128 * 40];
  __shared__ unsigned short Bh[128 * 40], Bl[128 * 40];
  const int m0 = blockIdx.x * 128;
  const int n0 = blockIdx.y * 128;
  const int tid = threadIdx.x;
  const int lane = tid & 63;
  const int wave = tid >> 6;
  const int wm = wave >> 1, wn = wave & 1;  // 2x2 waves
  const int lr = lane & 15;
  const int lk = (lane >> 4) * 8;

  f32x4 acc[4][4];
#pragma unroll
  for (int mi = 0; mi < 4; ++mi)
#pragma unroll
    for (int ni = 0; ni < 4; ++ni) acc[mi][ni] = (f32x4)0.0f;

  const int sr = tid >> 2;      // 0..63 staging row
  const int sq = (tid & 3) * 8; // k sub-offset in shorts

  for (int k0 = 0; k0 < H_; k0 += 32) {
    __syncthreads();  // previous iteration's frag reads done
#pragma unroll
    for (int it = 0; it < 2; ++it) {
      const int r = sr + it * 64;
      const size_t am = (size_t)(m0 + r) * H_ + k0 + sq;
      const int brow = (n0 + r < V_) ? (n0 + r) : (V_ - 1);
      const size_t bm = (size_t)brow * H_ + k0 + sq;
      *(float4*)&Ah[r * 40 + sq] = *(const float4*)&Ahi[am];
      *(float4*)&Al[r * 40 + sq] = *(const float4*)&Alo[am];
      *(float4*)&Bh[r * 40 + sq] = *(const float4*)&Bhi[bm];
      *(float4*)&Bl[r * 40 + sq] = *(const float4*)&Blo[bm];
    }
    __syncthreads();

    bf16x8 ah[4], al[4], bh[4], bl[4];
#pragma unroll
    for (int i = 0; i < 4; ++i) {
      ah[i] = *(const bf16x8*)&Ah[(wm * 64 + i * 16 + lr) * 40 + lk];
      al[i] = *(const bf16x8*)&Al[(wm * 64 + i * 16 + lr) * 40 + lk];
      bh[i] = *(const bf16x8*)&Bh[(wn * 64 + i * 16 + lr) * 40 + lk];
      bl[i] = *(const bf16x8*)&Bl[(wn * 64 + i * 16 + lr) * 40 + lk];
    }
#pragma unroll
    for (int mi = 0; mi < 4; ++mi)
#pragma unroll
      for (int ni = 0; ni < 4; ++ni) {
        acc[mi][ni] = __builtin_amdgcn_mfma_f32_16x16x32_bf16(
            ah[mi], bh[ni], acc[mi][ni], 0, 0, 0);
        acc[mi][ni] = __builtin_amdgcn_mfma_f32_16x16x32_bf16(
            ah[mi], bl[ni], acc[mi][ni], 0, 0, 0);
        acc[mi][ni] = __builtin_amdgcn_mfma_f32_16x16x32_bf16(
            al[mi], bh[ni], acc[mi][ni], 0, 0, 0);
      }
  }

#pragma unroll
  for (int ni = 0; ni < 4; ++ni) {
    const int v = n0 + wn * 64 + ni * 16 + lr;
    if (v >= V_) continue;
    const float bias = b_fc[v];
#pragma unroll
    for (int mi = 0; mi < 4; ++mi) {
      const int mrow = m0 + wm * 64 + mi * 16 + (lane >> 4) * 4;
#pragma unroll
      for (int r = 0; r < 4; ++r)
        out[(size_t)(mrow + r) * V_ + v] = acc[mi][ni][r] + bias;
    }
  }
}

// ---------------------------------------------------------------------------
// K4a: per-(b,v) online max+sum over S; stores (m, 1/sum).
// ---------------------------------------------------------------------------
__global__ __launch_bounds__(256) void k4_stats(const float* __restrict__ logits,
                                                float* __restrict__ stats) {
  const int g = blockIdx.x * 256 + threadIdx.x;
  const int b = g / V_;
  const int v = g - b * V_;
  const float* p = logits + (size_t)b * S_ * V_ + v;
  float m = -3.4e38f, sum = 0.f;
  for (int s = 0; s < S_; ++s) {
    const float xv = p[(size_t)s * V_];
    if (xv > m) {
      sum = sum * __expf(m - xv) + 1.f;
      m = xv;
    } else {
      sum += __expf(xv - m);
    }
  }
  stats[2 * g] = m;
  stats[2 * g + 1] = 1.f / sum;
}

// ---------------------------------------------------------------------------
// K4b: in-place normalize: out = exp(l - m) * inv_sum
// ---------------------------------------------------------------------------
__global__ __launch_bounds__(256) void k4_norm(float* __restrict__ logits,
                                               const float* __restrict__ stats) {
  const size_t idx = (size_t)blockIdx.x * 256 + threadIdx.x;
  const int v = (int)(idx % V_);
  const int b = (int)(idx / ((size_t)S_ * V_));
  const int g = b * V_ + v;
  const float m = stats[2 * g];
  const float inv = stats[2 * g + 1];
  logits[idx] = __expf(logits[idx] - m) * inv;
}

extern "C" void kernel_launch(void* const* d_in, const int* in_sizes, int n_in,
                              void* d_out, int out_size, void* d_ws,
                              size_t ws_size, hipStream_t stream) {
  const float* x    = (const float*)d_in[0];
  const float* W_ih = (const float*)d_in[1];
  const float* W_hh = (const float*)d_in[2];
  const float* b_ih = (const float*)d_in[3];
  const float* b_hh = (const float*)d_in[4];
  const float* W_fc = (const float*)d_in[5];
  const float* b_fc = (const float*)d_in[6];
  float* out = (float*)d_out;

  // ws layout (floats):
  //   xw (BS*H)  -- dead after k2_scan; reused for hs_hi/hs_lo bf16
  //   hs (BS*H) | stats (2*B*V) | part (u64: B*2*GPB*H) | wfc_hi/lo bf16
  float* ws = (float*)d_ws;
  float* xw    = ws;
  float* hs    = xw + (size_t)BS_ * H_;
  float* stats = hs + (size_t)BS_ * H_;
  unsigned long long* part =
      (unsigned long long*)(stats + (size_t)2 * B_ * V_);
  unsigned short* wfc_hi =
      (unsigned short*)(part + (size_t)B_ * 2 * GPB * H_);
  unsigned short* wfc_lo = wfc_hi + (size_t)V_ * H_;
  unsigned short* hs_hi = (unsigned short*)xw;  // overlay on dead xw
  unsigned short* hs_lo = hs_hi + (size_t)BS_ * H_;

  k0_init<<<(B_ * 2 * GPB * H_) / 256, 256, 0, stream>>>(part);
  k1_xw<<<dim3(BS_ / 16, H_ / 16), 256, 0, stream>>>(x, W_ih, b_ih, b_hh, xw);
  k5_split<<<((V_ * H_ / 4) + 255) / 256, 256, 0, stream>>>(W_fc, wfc_hi,
                                                            wfc_lo, V_ * H_ / 4);
  k2_scan<<<NBLK, 1024, 0, stream>>>(xw, W_hh, hs, part);
  k5_split<<<((BS_ * H_ / 4) + 255) / 256, 256, 0, stream>>>(
      hs, hs_hi, hs_lo, BS_ * H_ / 4);
  k3_logits<<<dim3(BS_ / 128, (V_ + 127) / 128), 256, 0, stream>>>(
      hs_hi, hs_lo, wfc_hi, wfc_lo, b_fc, out);
  k4_stats<<<(B_ * V_) / 256, 256, 0, stream>>>(out, stats);
  k4_norm<<<(int)((size_t)BS_ * V_ / 256), 256, 0, stream>>>(out, stats);
}